// Round 11
// baseline (178.245 us; speedup 1.0000x reference)
//
#include <hip/hip_runtime.h>
#include <hip/hip_bf16.h>

#define L 4096
#define DM 128
#define NH 8
#define HD 16
#define NBH 16
#define SK 41
#define NSPLIT 8
#define SLICE (L/NSPLIT)     // 512
#define NST (SLICE/32)       // 16 steps
// 0.25 * log2(e): folds the 1/sqrt(D) scale AND the exp->exp2 conversion into Q
#define QSCALE 0.36067376022224085f

typedef __attribute__((ext_vector_type(8))) short s16x8;
typedef __attribute__((ext_vector_type(4))) float f32x4;
typedef __attribute__((ext_vector_type(16))) float f32x16;

#define MFMA32(A,B,C) __builtin_amdgcn_mfma_f32_32x32x16_bf16(A,B,C,0,0,0)

__device__ __forceinline__ float bf2f(unsigned short h){ return __uint_as_float(((unsigned)h)<<16); }
__device__ __forceinline__ unsigned short f2bf(float f){
  unsigned u = __float_as_uint(f);
  u += 0x7FFFu + ((u>>16)&1u);
  return (unsigned short)(u>>16);
}
__device__ __forceinline__ float fast_exp2(float x){
  float r;
  asm("v_exp_f32 %0, %1" : "=v"(r) : "v"(x));
  return r;
}
// VALU-pipe exp2: Cephes degree-6 minimax on f in [-0.5,0.5], rel err ~3e-8.
// Runs on the vector ALU, concurrent with the v_exp_f32 transcendental pipe.
__device__ __forceinline__ float poly_exp2(float x){
  const float n = rintf(x);                 // v_rndne_f32
  const float f = x - n;                    // f in [-0.5, 0.5]
  float p = 1.535336188319500e-4f;
  p = fmaf(p, f, 1.339887440266574e-3f);
  p = fmaf(p, f, 9.618437357674640e-3f);
  p = fmaf(p, f, 5.550332471162809e-2f);
  p = fmaf(p, f, 2.402264791363012e-1f);
  p = fmaf(p, f, 6.931472028550421e-1f);
  p = fmaf(p, f, 1.0f);
  return ldexpf(p, (int)n);                 // v_cvt_i32 + v_ldexp_f32
}

// ---------------- K0: prep — split x to bf16 hi/lo; pack W's into MFMA frag layout ----------------
__global__ __launch_bounds__(256) void prep(
    const float* __restrict__ x,
    const float* __restrict__ Wq, const float* __restrict__ Wk,
    const float* __restrict__ Wv, const float* __restrict__ Wo,
    unsigned short* __restrict__ Xh, unsigned short* __restrict__ Xl,
    unsigned short* __restrict__ Wph, unsigned short* __restrict__ Wpl)
{
  const int t = threadIdx.x;
  const int blk = blockIdx.x;
  if (blk < 1024){
    const long base = (long)blk*1024 + t*4;
    float4 v = *(const float4*)(x + base);
    unsigned short h[4], lo[4];
    h[0]=f2bf(v.x); lo[0]=f2bf(v.x - bf2f(h[0]));
    h[1]=f2bf(v.y); lo[1]=f2bf(v.y - bf2f(h[1]));
    h[2]=f2bf(v.z); lo[2]=f2bf(v.z - bf2f(h[2]));
    h[3]=f2bf(v.w); lo[3]=f2bf(v.w - bf2f(h[3]));
    *(uint2*)(Xh+base) = *(uint2*)h;
    *(uint2*)(Xl+base) = *(uint2*)lo;
  } else {
    const int e = (blk-1024)*256 + t;   // 0..65535
    const int p = e >> 14;
    const int idx = e & 16383;
    const int j = idx & 7;
    const int f = idx >> 3;
    const int n = f & 127;
    const int kcg = f >> 7;             // 0..15
    const int k = (kcg>>1)*16 + (kcg&1)*8 + j;
    const float* W = (p==0)?Wq:((p==1)?Wk:((p==2)?Wv:Wo));
    const float v = W[k*128 + n];
    const unsigned short h = f2bf(v);
    Wph[e] = h;
    Wpl[e] = f2bf(v - bf2f(h));
  }
}

// ---------------- K1: MFMA QKV projection (Q pre-scaled by QSCALE) ----------------
__global__ __launch_bounds__(256) void proj_mfma(
    const unsigned short* __restrict__ Xh, const unsigned short* __restrict__ Xl,
    const unsigned short* __restrict__ Wph, const unsigned short* __restrict__ Wpl,
    const float* __restrict__ bq, const float* __restrict__ bk, const float* __restrict__ bv,
    unsigned short* __restrict__ Qh, unsigned short* __restrict__ Ql,
    unsigned short* __restrict__ Kh, unsigned short* __restrict__ Kl,
    float* __restrict__ Vo)
{
  const int p = blockIdx.y;
  const float* __restrict__ bias = (p==0)?bq:((p==1)?bk:bv);
  __shared__ __align__(16) unsigned short wh[16384];
  __shared__ __align__(16) unsigned short wl[16384];
  const int t = threadIdx.x;
  {
    const uint4* gh = (const uint4*)(Wph + (long)p*16384);
    const uint4* gl = (const uint4*)(Wpl + (long)p*16384);
    uint4* sh = (uint4*)wh; uint4* sl = (uint4*)wl;
#pragma unroll
    for (int i=0;i<8;++i){ sh[t + i*256] = gh[t + i*256]; sl[t + i*256] = gl[t + i*256]; }
  }
  __syncthreads();
  const int w = t>>6, l = t&63;
  const int lc = l&15, g = l>>4;
  const int mbase = blockIdx.x*128 + w*32;
  f32x4 acc[2][8];
#pragma unroll
  for (int mt=0;mt<2;++mt)
#pragma unroll
    for (int nt=0;nt<8;++nt){ acc[mt][nt][0]=0.f; acc[mt][nt][1]=0.f; acc[mt][nt][2]=0.f; acc[mt][nt][3]=0.f; }
  const unsigned short* __restrict__ Asrc = (g<2)? Xh : Xl;
  const int koff = (g&1)*8;
  for (int kc=0; kc<8; ++kc){
    s16x8 a[2];
#pragma unroll
    for (int mt=0;mt<2;++mt)
      a[mt] = *(const s16x8*)(Asrc + ((long)(mbase + mt*16 + lc))*128 + kc*16 + koff);
#pragma unroll
    for (int nt=0;nt<8;++nt){
      const int fi = (kc*2+(g&1))*128 + nt*16 + lc;
      s16x8 b1 = ((const s16x8*)wh)[fi];
      s16x8 b2 = ((const s16x8*)wl)[fi];
#pragma unroll
      for (int mt=0;mt<2;++mt){
        acc[mt][nt] = __builtin_amdgcn_mfma_f32_16x16x32_bf16(a[mt], b1, acc[mt][nt], 0,0,0);
        acc[mt][nt] = __builtin_amdgcn_mfma_f32_16x16x32_bf16(a[mt], b2, acc[mt][nt], 0,0,0);
      }
    }
  }
#pragma unroll
  for (int nt=0;nt<8;++nt){
    const float bb = bias[nt*16 + lc];
#pragma unroll
    for (int mt=0;mt<2;++mt){
#pragma unroll
      for (int r=0;r<4;++r){
        const int row = mbase + mt*16 + g*4 + r;
        float v = acc[mt][nt][r] + bb;
        const int b = row>>12, li = row&4095;
        const long o = (((long)(b*NH + nt))*L + li)*HD + lc;
        if (p==2){
          Vo[o] = v;
        } else {
          if (p==0) v *= QSCALE;
          const unsigned short h = f2bf(v);
          const unsigned short lo2 = f2bf(v - bf2f(h));
          if (p==0){ Qh[o]=h; Ql[o]=lo2; } else { Kh[o]=h; Kl[o]=lo2; }
        }
      }
    }
  }
}

// ---------------- K2: partial row-max via 32x32x16 MFMA, 4 A-tiles, depth-1 prefetch ----------------
__global__ __launch_bounds__(256) void rowmax_k(
    const unsigned short* __restrict__ Qh, const unsigned short* __restrict__ Ql,
    const unsigned short* __restrict__ Kh, const unsigned short* __restrict__ Kl,
    float* __restrict__ mpart)
{
  const int bh = blockIdx.y, qt = blockIdx.x, ks = blockIdx.z;
  const int t = threadIdx.x, w = t>>6, l = t&63;
  const int lk = l&31, ks8 = (l>>5)*8;
  const int qbase = qt*512 + w*128;
  s16x8 ah0,ah1,ah2,ah3, al0,al1,al2,al3;
  {
    const long r0 = ((long)bh*L + qbase + lk)*HD + ks8;
    ah0 = *(const s16x8*)(Qh + r0);          al0 = *(const s16x8*)(Ql + r0);
    ah1 = *(const s16x8*)(Qh + r0 + 32*HD);  al1 = *(const s16x8*)(Ql + r0 + 32*HD);
    ah2 = *(const s16x8*)(Qh + r0 + 64*HD);  al2 = *(const s16x8*)(Ql + r0 + 64*HD);
    ah3 = *(const s16x8*)(Qh + r0 + 96*HD);  al3 = *(const s16x8*)(Ql + r0 + 96*HD);
  }
  f32x16 fz, m0, m1, m2, m3;
#pragma unroll
  for (int r=0;r<16;++r){ fz[r]=0.f; m0[r]=-3.4e38f; m1[r]=-3.4e38f; m2[r]=-3.4e38f; m3[r]=-3.4e38f; }
  const unsigned short* khp = Kh + ((long)bh*L + ks*SLICE + lk)*HD + ks8;
  const unsigned short* klp = Kl + ((long)bh*L + ks*SLICE + lk)*HD + ks8;
  s16x8 cb1 = *(const s16x8*)khp;
  s16x8 cb2 = *(const s16x8*)klp;
  for (int st=0; st<NST; ++st){
    s16x8 nb1 = *(const s16x8*)(khp + (st+1)*32*HD);   // over-read on last iter: adjacent alloc, unused
    s16x8 nb2 = *(const s16x8*)(klp + (st+1)*32*HD);
    f32x16 x0 = MFMA32(ah0,cb1,fz); x0 = MFMA32(al0,cb1,x0); x0 = MFMA32(ah0,cb2,x0);
    f32x16 x1 = MFMA32(ah1,cb1,fz); x1 = MFMA32(al1,cb1,x1); x1 = MFMA32(ah1,cb2,x1);
#pragma unroll
    for (int r=0;r<16;++r){ m0[r] = fmaxf(m0[r], x0[r]); m1[r] = fmaxf(m1[r], x1[r]); }
    f32x16 x2 = MFMA32(ah2,cb1,fz); x2 = MFMA32(al2,cb1,x2); x2 = MFMA32(ah2,cb2,x2);
    f32x16 x3 = MFMA32(ah3,cb1,fz); x3 = MFMA32(al3,cb1,x3); x3 = MFMA32(ah3,cb2,x3);
#pragma unroll
    for (int r=0;r<16;++r){ m2[r] = fmaxf(m2[r], x2[r]); m3[r] = fmaxf(m3[r], x3[r]); }
    cb1 = nb1; cb2 = nb2;
  }
  const long obase = ((long)ks*NBH + bh)*L + qbase + 4*(l>>5);
#pragma unroll
  for (int r=0;r<16;++r){
    float v0=m0[r], v1=m1[r], v2=m2[r], v3=m3[r];
    v0=fmaxf(v0,__shfl_xor(v0,1));  v1=fmaxf(v1,__shfl_xor(v1,1));  v2=fmaxf(v2,__shfl_xor(v2,1));  v3=fmaxf(v3,__shfl_xor(v3,1));
    v0=fmaxf(v0,__shfl_xor(v0,2));  v1=fmaxf(v1,__shfl_xor(v1,2));  v2=fmaxf(v2,__shfl_xor(v2,2));  v3=fmaxf(v3,__shfl_xor(v3,2));
    v0=fmaxf(v0,__shfl_xor(v0,4));  v1=fmaxf(v1,__shfl_xor(v1,4));  v2=fmaxf(v2,__shfl_xor(v2,4));  v3=fmaxf(v3,__shfl_xor(v3,4));
    v0=fmaxf(v0,__shfl_xor(v0,8));  v1=fmaxf(v1,__shfl_xor(v1,8));  v2=fmaxf(v2,__shfl_xor(v2,8));  v3=fmaxf(v3,__shfl_xor(v3,8));
    v0=fmaxf(v0,__shfl_xor(v0,16)); v1=fmaxf(v1,__shfl_xor(v1,16)); v2=fmaxf(v2,__shfl_xor(v2,16)); v3=fmaxf(v3,__shfl_xor(v3,16));
    if (lk == 0){
      const int rmap = (r&3) + 8*(r>>2);
      mpart[obase + rmap]      = v0;
      mpart[obase + 32 + rmap] = v1;
      mpart[obase + 64 + rmap] = v2;
      mpart[obase + 96 + rmap] = v3;
    }
  }
}

// ---------------- K2b: reduce partial maxes -> w_q = exp2(-m'_q) ----------------
__global__ __launch_bounds__(256) void mreduce(
    const float* __restrict__ mpart, float* __restrict__ wq)
{
  const int i = blockIdx.x*256 + threadIdx.x;  // 0 .. NBH*L-1
  float m = -3.4e38f;
#pragma unroll
  for (int p=0;p<NSPLIT;++p) m = fmaxf(m, mpart[(long)p*NBH*L + i]);
  wq[i] = fast_exp2(-m);
}

// ---------------- K3: partial column sums via 32x32x16 MFMA, dual-pipe exp ----------------
// Half the exps go to the transcendental pipe (v_exp_f32), half to the VALU pipe
// (degree-6 poly) — the two pipes execute concurrently.
__global__ __launch_bounds__(256) void colexp_k(
    const unsigned short* __restrict__ Kh, const unsigned short* __restrict__ Kl,
    const unsigned short* __restrict__ Qh, const unsigned short* __restrict__ Ql,
    const float* __restrict__ wq, float* __restrict__ cspart)
{
  const int bh = blockIdx.y, kt = blockIdx.x, qs = blockIdx.z;
  const int t = threadIdx.x, w = t>>6, l = t&63;
  const int lk = l&31, ks8 = (l>>5)*8;
  const int kbase = kt*512 + w*128;
  s16x8 ah0,ah1,ah2,ah3, al0,al1,al2,al3;
  {
    const long r0 = ((long)bh*L + kbase + lk)*HD + ks8;
    ah0 = *(const s16x8*)(Kh + r0);          al0 = *(const s16x8*)(Kl + r0);
    ah1 = *(const s16x8*)(Kh + r0 + 32*HD);  al1 = *(const s16x8*)(Kl + r0 + 32*HD);
    ah2 = *(const s16x8*)(Kh + r0 + 64*HD);  al2 = *(const s16x8*)(Kl + r0 + 64*HD);
    ah3 = *(const s16x8*)(Kh + r0 + 96*HD);  al3 = *(const s16x8*)(Kl + r0 + 96*HD);
  }
  f32x16 fz, cs0, cs1, cs2, cs3;
#pragma unroll
  for (int r=0;r<16;++r){ fz[r]=0.f; cs0[r]=0.f; cs1[r]=0.f; cs2[r]=0.f; cs3[r]=0.f; }
  const unsigned short* qhp = Qh + ((long)bh*L + qs*SLICE + lk)*HD + ks8;
  const unsigned short* qlp = Ql + ((long)bh*L + qs*SLICE + lk)*HD + ks8;
  const float* wgp = wq + (long)bh*L + qs*SLICE + lk;
  s16x8 cb1 = *(const s16x8*)qhp;
  s16x8 cb2 = *(const s16x8*)qlp;
  float cw = wgp[0];
  for (int st=0; st<NST; ++st){
    s16x8 nb1 = *(const s16x8*)(qhp + (st+1)*32*HD);   // over-read on last iter: adjacent alloc, unused
    s16x8 nb2 = *(const s16x8*)(qlp + (st+1)*32*HD);
    const float nw = wgp[(st+1)*32];
    f32x16 x0 = MFMA32(ah0,cb1,fz); x0 = MFMA32(al0,cb1,x0); x0 = MFMA32(ah0,cb2,x0);
    f32x16 x1 = MFMA32(ah1,cb1,fz); x1 = MFMA32(al1,cb1,x1); x1 = MFMA32(ah1,cb2,x1);
#pragma unroll
    for (int r=0;r<16;++r){
      const float e0 = (r&1) ? poly_exp2(x0[r]) : fast_exp2(x0[r]);
      const float e1 = (r&1) ? fast_exp2(x1[r]) : poly_exp2(x1[r]);
      cs0[r] = fmaf(e0, cw, cs0[r]);
      cs1[r] = fmaf(e1, cw, cs1[r]);
    }
    f32x16 x2 = MFMA32(ah2,cb1,fz); x2 = MFMA32(al2,cb1,x2); x2 = MFMA32(ah2,cb2,x2);
    f32x16 x3 = MFMA32(ah3,cb1,fz); x3 = MFMA32(al3,cb1,x3); x3 = MFMA32(ah3,cb2,x3);
#pragma unroll
    for (int r=0;r<16;++r){
      const float e2 = (r&1) ? poly_exp2(x2[r]) : fast_exp2(x2[r]);
      const float e3 = (r&1) ? fast_exp2(x3[r]) : poly_exp2(x3[r]);
      cs2[r] = fmaf(e2, cw, cs2[r]);
      cs3[r] = fmaf(e3, cw, cs3[r]);
    }
    cb1 = nb1; cb2 = nb2; cw = nw;
  }
  const long obase = ((long)qs*NBH + bh)*L + kbase + 4*(l>>5);
#pragma unroll
  for (int r=0;r<16;++r){
    float v0=cs0[r], v1=cs1[r], v2=cs2[r], v3=cs3[r];
    v0+=__shfl_xor(v0,1);  v1+=__shfl_xor(v1,1);  v2+=__shfl_xor(v2,1);  v3+=__shfl_xor(v3,1);
    v0+=__shfl_xor(v0,2);  v1+=__shfl_xor(v1,2);  v2+=__shfl_xor(v2,2);  v3+=__shfl_xor(v3,2);
    v0+=__shfl_xor(v0,4);  v1+=__shfl_xor(v1,4);  v2+=__shfl_xor(v2,4);  v3+=__shfl_xor(v3,4);
    v0+=__shfl_xor(v0,8);  v1+=__shfl_xor(v1,8);  v2+=__shfl_xor(v2,8);  v3+=__shfl_xor(v3,8);
    v0+=__shfl_xor(v0,16); v1+=__shfl_xor(v1,16); v2+=__shfl_xor(v2,16); v3+=__shfl_xor(v3,16);
    if (lk == 0){
      const int rmap = (r&3) + 8*(r>>2);
      cspart[obase + rmap]      = v0;
      cspart[obase + 32 + rmap] = v1;
      cspart[obase + 64 + rmap] = v2;
      cspart[obase + 96 + rmap] = v3;
    }
  }
}

// ---------------- K4: exact 3-level radix-select top-41 + gather Ks/Vs (csreduce fused) ----------------
__global__ __launch_bounds__(256) void topk_gather(
    const float* __restrict__ cspart,
    const unsigned short* __restrict__ Kh, const unsigned short* __restrict__ Kl,
    const float* __restrict__ V,
    float* __restrict__ Ks, float* __restrict__ Vs)
{
  const int bh = blockIdx.x;
  const int t = threadIdx.x;
  __shared__ float vals[4096];
  __shared__ unsigned hist[2048];
  __shared__ unsigned suf[256];
  __shared__ int meta[4];           // 0:B 1:nab 2:ngt 3:ntie
  __shared__ int sel[SK];
  __shared__ int sorted[SK];
  __shared__ int tiei[4096];

  for (int i=t; i<1024; i+=256){
    float4 s = {0.f,0.f,0.f,0.f};
#pragma unroll
    for (int p=0;p<NSPLIT;++p){
      float4 v = *(const float4*)(cspart + ((long)p*NBH + bh)*L + i*4);
      s.x += v.x; s.y += v.y; s.z += v.z; s.w += v.w;
    }
    *(float4*)&vals[i*4] = s;
  }
  __syncthreads();

  int target = SK;
  unsigned B1 = 0, P2 = 0, T = 0;
#pragma unroll
  for (int pass=0; pass<3; ++pass){
    const int nb = (pass<2) ? 2048 : 1024;
    const int chunk = nb >> 8;
    for (int i=t;i<nb;i+=256) hist[i]=0u;
    __syncthreads();
    for (int i=t;i<4096;i+=256){
      const unsigned u = __float_as_uint(vals[i]);
      bool ok; int bk;
      if (pass==0){ ok = true;              bk = (int)(u>>21); }
      else if (pass==1){ ok = ((u>>21)==B1); bk = (int)((u>>10)&0x7FFu); }
      else { ok = ((u>>10)==P2);            bk = (int)(u&0x3FFu); }
      if (ok) atomicAdd(&hist[bk], 1u);
    }
    __syncthreads();
    {
      unsigned c=0;
#pragma unroll
      for (int b=0;b<8;++b) if (b<chunk) c += hist[t*chunk+b];
      suf[t]=c;
    }
    __syncthreads();
    for (int off=1; off<256; off<<=1){
      unsigned add = (t+off<256)? suf[t+off] : 0u;
      __syncthreads();
      suf[t] += add;
      __syncthreads();
    }
    {
      const unsigned mysuf = suf[t];
      const unsigned nxt = (t==255)?0u:suf[t+1];
      if (mysuf >= (unsigned)target && nxt < (unsigned)target){
        unsigned running = nxt;
        for (int b=t*chunk+chunk-1; b>=t*chunk; --b){
          const unsigned h = hist[b];
          if (running + h >= (unsigned)target){ meta[0]=b; meta[1]=(int)running; break; }
          running += h;
        }
      }
    }
    __syncthreads();
    const unsigned B = (unsigned)meta[0];
    target -= meta[1];
    if (pass==0) B1 = B;
    else if (pass==1) P2 = (B1<<11)|B;
    else T = (P2<<10)|B;
    __syncthreads();
  }
  if (t==0){ meta[2]=0; meta[3]=0; }
  __syncthreads();
  for (int i=t;i<4096;i+=256){
    const unsigned u = __float_as_uint(vals[i]);
    if (u > T){ int p = atomicAdd(&meta[2],1); sel[p]=i; }
    else if (u == T){ int p = atomicAdd(&meta[3],1); tiei[p]=i; }
  }
  __syncthreads();
  const int ngt = meta[2];
  const int ntie = meta[3];
  for (int j=t; j<ntie; j+=256){
    const int x = tiei[j];
    int rk=0;
    for (int k=0;k<ntie;++k) rk += (tiei[k] < x);
    if (rk < target) sel[ngt+rk] = x;
  }
  __syncthreads();
  if (t<SK){
    int x=sel[t]; int rk=0;
    for (int j=0;j<SK;++j) rk += (sel[j]<x);
    sorted[rk]=x;
  }
  __syncthreads();
  for (int i=t;i<SK*HD;i+=256){
    const int j=i>>4, dd=i&15;
    const int key=sorted[j];
    const long src=((long)bh*L+key)*HD+dd;
    Ks[(long)bh*SK*HD+i]=bf2f(Kh[src])+bf2f(Kl[src]);
    Vs[(long)bh*SK*HD+i]=V[src];
  }
}

// ---------------- K5: sampled attention — lane-pair split over keys ----------------
__global__ __launch_bounds__(256) void sattn(
    const unsigned short* __restrict__ Qh, const unsigned short* __restrict__ Ql,
    const float* __restrict__ Ks, const float* __restrict__ Vs,
    unsigned short* __restrict__ AOh, unsigned short* __restrict__ AOl)
{
  const int bh = blockIdx.y, qb = blockIdx.x;
  const int t = threadIdx.x;
  __shared__ float ks[SK*HD], vs[SK*HD];
  for (int i=t; i<SK*HD; i+=256){
    ks[i] = Ks[(long)bh*SK*HD + i];
    vs[i] = Vs[(long)bh*SK*HD + i];
  }
  __syncthreads();
  const int q = qb*128 + (t>>1);
  const int half = t&1;
  const long qo = ((long)bh*L + q)*HD;
  float qv[16];
  {
    s16x8 h0 = *(const s16x8*)(Qh+qo);
    s16x8 h1 = *(const s16x8*)(Qh+qo+8);
    s16x8 l0 = *(const s16x8*)(Ql+qo);
    s16x8 l1 = *(const s16x8*)(Ql+qo+8);
#pragma unroll
    for (int d=0; d<8; ++d){
      qv[d]   = bf2f((unsigned short)h0[d]) + bf2f((unsigned short)l0[d]);
      qv[d+8] = bf2f((unsigned short)h1[d]) + bf2f((unsigned short)l1[d]);
    }
  }
  float mrun = -3.4e38f, lrun = 0.f, out[16];
#pragma unroll
  for (int d=0; d<16; ++d) out[d] = 0.f;
  for (int j=half; j<SK; j+=2){
    float4 k0 = *(const float4*)&ks[j*HD+0];
    float4 k1 = *(const float4*)&ks[j*HD+4];
    float4 k2 = *(const float4*)&ks[j*HD+8];
    float4 k3 = *(const float4*)&ks[j*HD+12];
    float s = qv[0]*k0.x;
    s = fmaf(qv[1],k0.y,s); s = fmaf(qv[2],k0.z,s); s = fmaf(qv[3],k0.w,s);
    s = fmaf(qv[4],k1.x,s); s = fmaf(qv[5],k1.y,s); s = fmaf(qv[6],k1.z,s); s = fmaf(qv[7],k1.w,s);
    s = fmaf(qv[8],k2.x,s); s = fmaf(qv[9],k2.y,s); s = fmaf(qv[10],k2.z,s); s = fmaf(qv[11],k2.w,s);
    s = fmaf(qv[12],k3.x,s); s = fmaf(qv[13],k3.y,s); s = fmaf(qv[14],k3.z,s); s = fmaf(qv[15],k3.w,s);
    if (s > mrun){
      const float c = fast_exp2(mrun - s);
      lrun *= c;
#pragma unroll
      for (int d=0; d<16; ++d) out[d] *= c;
      mrun = s;
    }
    const float p = fast_exp2(s - mrun);
    lrun += p;
    float4 v0 = *(const float4*)&vs[j*HD+0];
    float4 v1 = *(const float4*)&vs[j*HD+4];
    float4 v2 = *(const float4*)&vs[j*HD+8];
    float4 v3 = *(const float4*)&vs[j*HD+12];
    out[0]=fmaf(p,v0.x,out[0]); out[1]=fmaf(p,v0.y,out[1]); out[2]=fmaf(p,v0.z,out[2]); out[3]=fmaf(p,v0.w,out[3]);
    out[4]=fmaf(p,v1.x,out[4]); out[5]=fmaf(p,v1.y,out[5]); out[6]=fmaf(p,v1.z,out[6]); out[7]=fmaf(p,v1.w,out[7]);
    out[8]=fmaf(p,v2.x,out[8]); out[9]=fmaf(p,v2.y,out[9]); out[10]=fmaf(p,v2.z,out[10]); out[11]=fmaf(p,v2.w,out[11]);
    out[12]=fmaf(p,v3.x,out[12]); out[13]=fmaf(p,v3.y,out[13]); out[14]=fmaf(p,v3.z,out[14]); out[15]=fmaf(p,v3.w,out[15]);
  }
  // merge lane-pair online-softmax states
  const float mo = __shfl_xor(mrun, 1);
  const float lo = __shfl_xor(lrun, 1);
  const float mm = fmaxf(mrun, mo);
  const float cs_ = fast_exp2(mrun - mm);
  const float co_ = fast_exp2(mo - mm);
  const float ltot = fmaf(lrun, cs_, lo*co_);
  const float inv = 1.f / ltot;
#pragma unroll
  for (int d=0; d<16; ++d){
    const float ov = __shfl_xor(out[d], 1);
    out[d] = fmaf(out[d]*cs_, inv, ov*co_*inv);
  }
  if (half == 0){
    const int b = bh>>3, h = bh&7;
    const long row = (long)b*L + q;
    unsigned short hv[16], lv[16];
#pragma unroll
    for (int d=0; d<16; ++d){
      const float v = out[d];
      hv[d] = f2bf(v);
      lv[d] = f2bf(v - bf2f(hv[d]));
    }
    unsigned short* oh = AOh + row*DM + h*HD;
    unsigned short* ol = AOl + row*DM + h*HD;
    *(uint4*)(oh)   = *(uint4*)(hv);
    *(uint4*)(oh+8) = *(uint4*)(hv+8);
    *(uint4*)(ol)   = *(uint4*)(lv);
    *(uint4*)(ol+8) = *(uint4*)(lv+8);
  }
}

// ---------------- K6: MFMA output projection ----------------
__global__ __launch_bounds__(256) void outproj_mfma(
    const unsigned short* __restrict__ AOh, const unsigned short* __restrict__ AOl,
    const unsigned short* __restrict__ Wph, const unsigned short* __restrict__ Wpl,
    const float* __restrict__ bo, float* __restrict__ out)
{
  __shared__ __align__(16) unsigned short wh[16384];
  __shared__ __align__(16) unsigned short wl[16384];
  const int t = threadIdx.x;
  {
    const uint4* gh = (const uint4*)(Wph + (long)3*16384);
    const uint4* gl = (const uint4*)(Wpl + (long)3*16384);
    uint4* sh = (uint4*)wh; uint4* sl = (uint4*)wl;
#pragma unroll
    for (int i=0;i<8;++i){ sh[t + i*256] = gh[t + i*256]; sl[t + i*256] = gl[t + i*256]; }
  }
  __syncthreads();
  const int w = t>>6, l = t&63;
  const int lc = l&15, g = l>>4;
  const int mbase = blockIdx.x*128 + w*32;
  f32x4 acc[2][8];
#pragma unroll
  for (int mt=0;mt<2;++mt)
#pragma unroll
    for (int nt=0;nt<8;++nt){ acc[mt][nt][0]=0.f; acc[mt][nt][1]=0.f; acc[mt][nt][2]=0.f; acc[mt][nt][3]=0.f; }
  const unsigned short* __restrict__ Asrc = (g<2)? AOh : AOl;
  const int koff = (g&1)*8;
  for (int kc=0; kc<8; ++kc){
    s16x8 a[2];
#pragma unroll
    for (int mt=0;mt<2;++mt)
      a[mt] = *(const s16x8*)(Asrc + ((long)(mbase + mt*16 + lc))*128 + kc*16 + koff);
#pragma unroll
    for (int nt=0;nt<8;++nt){
      const int fi = (kc*2+(g&1))*128 + nt*16 + lc;
      s16x8 b1 = ((const s16x8*)wh)[fi];
      s16x8 b2 = ((const s16x8*)wl)[fi];
#pragma unroll
      for (int mt=0;mt<2;++mt){
        acc[mt][nt] = __builtin_amdgcn_mfma_f32_16x16x32_bf16(a[mt], b1, acc[mt][nt], 0,0,0);
        acc[mt][nt] = __builtin_amdgcn_mfma_f32_16x16x32_bf16(a[mt], b2, acc[mt][nt], 0,0,0);
      }
    }
  }
#pragma unroll
  for (int nt=0;nt<8;++nt){
    const float bb = bo[nt*16 + lc];
#pragma unroll
    for (int mt=0;mt<2;++mt){
#pragma unroll
      for (int r=0;r<4;++r){
        const int row = mbase + mt*16 + g*4 + r;
        out[(long)row*DM + nt*16 + lc] = acc[mt][nt][r] + bb;
      }
    }
  }
}

extern "C" void kernel_launch(void* const* d_in, const int* in_sizes, int n_in,
                              void* d_out, int out_size, void* d_ws, size_t ws_size,
                              hipStream_t stream)
{
  const float* x  = (const float*)d_in[0];
  const float* Wq = (const float*)d_in[1];
  const float* bq = (const float*)d_in[2];
  const float* Wk = (const float*)d_in[3];
  const float* bk = (const float*)d_in[4];
  const float* Wv = (const float*)d_in[5];
  const float* bv = (const float*)d_in[6];
  const float* Wo = (const float*)d_in[7];
  const float* bo = (const float*)d_in[8];
  float* out = (float*)d_out;

  char* wsp = (char*)d_ws;
  size_t o = 0;
  auto alloc = [&](size_t bytes)->char*{
    char* p = wsp + o; o += (bytes + 255) & ~(size_t)255; return p;
  };
  unsigned short* Qh = (unsigned short*)alloc((size_t)NBH*L*HD*2);
  unsigned short* Ql = (unsigned short*)alloc((size_t)NBH*L*HD*2);
  unsigned short* Kh = (unsigned short*)alloc((size_t)NBH*L*HD*2);
  unsigned short* Kl = (unsigned short*)alloc((size_t)NBH*L*HD*2);
  float* Vv    = (float*)alloc((size_t)NBH*L*HD*4);
  float* mpart = (float*)alloc((size_t)NSPLIT*NBH*L*4);
  float* cspart= (float*)alloc((size_t)NSPLIT*NBH*L*4);
  float* wqv   = (float*)alloc((size_t)NBH*L*4);
  float* Ks    = (float*)alloc((size_t)NBH*SK*HD*4);
  float* Vs    = (float*)alloc((size_t)NBH*SK*HD*4);
  unsigned short* Xh  = (unsigned short*)alloc((size_t)2*L*DM*2);
  unsigned short* Xl  = (unsigned short*)alloc((size_t)2*L*DM*2);
  unsigned short* AOh = (unsigned short*)alloc((size_t)2*L*DM*2);
  unsigned short* AOl = (unsigned short*)alloc((size_t)2*L*DM*2);
  unsigned short* Wph = (unsigned short*)alloc((size_t)4*16384*2);
  unsigned short* Wpl = (unsigned short*)alloc((size_t)4*16384*2);

  prep<<<1280,256,0,stream>>>(x,Wq,Wk,Wv,Wo,Xh,Xl,Wph,Wpl);
  proj_mfma<<<dim3(64,3),256,0,stream>>>(Xh,Xl,Wph,Wpl,bq,bk,bv,Qh,Ql,Kh,Kl,Vv);
  rowmax_k<<<dim3(8,16,NSPLIT),256,0,stream>>>(Qh,Ql,Kh,Kl,mpart);
  mreduce<<<NBH*L/256,256,0,stream>>>(mpart,wqv);
  colexp_k<<<dim3(8,16,NSPLIT),256,0,stream>>>(Kh,Kl,Qh,Ql,wqv,cspart);
  topk_gather<<<16,256,0,stream>>>(cspart,Kh,Kl,Vv,Ks,Vs);
  sattn<<<dim3(32,16),256,0,stream>>>(Qh,Ql,Ks,Vs,AOh,AOl);
  outproj_mfma<<<64,256,0,stream>>>(AOh,AOl,Wph,Wpl,bo,out);
}

// Round 12
// 136.212 us; speedup vs baseline: 1.3086x; 1.3086x over previous
//
#include <hip/hip_runtime.h>
#include <hip/hip_bf16.h>

#define L 4096
#define DM 128
#define NH 8
#define HD 16
#define NBH 16
#define SK 41
#define NSPLIT 8
#define SLICE (L/NSPLIT)     // 512
#define KK (SLICE/16)        // 32
// 0.25 * log2(e): folds the 1/sqrt(D) scale AND the exp->exp2 conversion into Q
#define QSCALE 0.36067376022224085f

typedef __attribute__((ext_vector_type(8))) short s16x8;
typedef __attribute__((ext_vector_type(4))) float f32x4;

__device__ __forceinline__ float bf2f(unsigned short h){ return __uint_as_float(((unsigned)h)<<16); }
__device__ __forceinline__ unsigned short f2bf(float f){
  unsigned u = __float_as_uint(f);
  u += 0x7FFFu + ((u>>16)&1u);
  return (unsigned short)(u>>16);
}
__device__ __forceinline__ float fast_exp2(float x){
  float r;
  asm("v_exp_f32 %0, %1" : "=v"(r) : "v"(x));
  return r;
}

// ---------------- K0: prep — split x to bf16 hi/lo; pack W's into MFMA frag layout ----------------
__global__ __launch_bounds__(256) void prep(
    const float* __restrict__ x,
    const float* __restrict__ Wq, const float* __restrict__ Wk,
    const float* __restrict__ Wv, const float* __restrict__ Wo,
    unsigned short* __restrict__ Xh, unsigned short* __restrict__ Xl,
    unsigned short* __restrict__ Wph, unsigned short* __restrict__ Wpl)
{
  const int t = threadIdx.x;
  const int blk = blockIdx.x;
  if (blk < 1024){
    const long base = (long)blk*1024 + t*4;
    float4 v = *(const float4*)(x + base);
    unsigned short h[4], lo[4];
    h[0]=f2bf(v.x); lo[0]=f2bf(v.x - bf2f(h[0]));
    h[1]=f2bf(v.y); lo[1]=f2bf(v.y - bf2f(h[1]));
    h[2]=f2bf(v.z); lo[2]=f2bf(v.z - bf2f(h[2]));
    h[3]=f2bf(v.w); lo[3]=f2bf(v.w - bf2f(h[3]));
    *(uint2*)(Xh+base) = *(uint2*)h;
    *(uint2*)(Xl+base) = *(uint2*)lo;
  } else {
    const int e = (blk-1024)*256 + t;   // 0..65535
    const int p = e >> 14;
    const int idx = e & 16383;
    const int j = idx & 7;
    const int f = idx >> 3;
    const int n = f & 127;
    const int kcg = f >> 7;             // 0..15
    const int k = (kcg>>1)*16 + (kcg&1)*8 + j;
    const float* W = (p==0)?Wq:((p==1)?Wk:((p==2)?Wv:Wo));
    const float v = W[k*128 + n];
    const unsigned short h = f2bf(v);
    Wph[e] = h;
    Wpl[e] = f2bf(v - bf2f(h));
  }
}

// ---------------- K1: MFMA QKV projection (Q pre-scaled by QSCALE) ----------------
__global__ __launch_bounds__(256) void proj_mfma(
    const unsigned short* __restrict__ Xh, const unsigned short* __restrict__ Xl,
    const unsigned short* __restrict__ Wph, const unsigned short* __restrict__ Wpl,
    const float* __restrict__ bq, const float* __restrict__ bk, const float* __restrict__ bv,
    unsigned short* __restrict__ Qh, unsigned short* __restrict__ Ql,
    unsigned short* __restrict__ Kh, unsigned short* __restrict__ Kl,
    float* __restrict__ Vo)
{
  const int p = blockIdx.y;
  const float* __restrict__ bias = (p==0)?bq:((p==1)?bk:bv);
  __shared__ __align__(16) unsigned short wh[16384];
  __shared__ __align__(16) unsigned short wl[16384];
  const int t = threadIdx.x;
  {
    const uint4* gh = (const uint4*)(Wph + (long)p*16384);
    const uint4* gl = (const uint4*)(Wpl + (long)p*16384);
    uint4* sh = (uint4*)wh; uint4* sl = (uint4*)wl;
#pragma unroll
    for (int i=0;i<8;++i){ sh[t + i*256] = gh[t + i*256]; sl[t + i*256] = gl[t + i*256]; }
  }
  __syncthreads();
  const int w = t>>6, l = t&63;
  const int lc = l&15, g = l>>4;
  const int mbase = blockIdx.x*128 + w*32;
  f32x4 acc[2][8];
#pragma unroll
  for (int mt=0;mt<2;++mt)
#pragma unroll
    for (int nt=0;nt<8;++nt){ acc[mt][nt][0]=0.f; acc[mt][nt][1]=0.f; acc[mt][nt][2]=0.f; acc[mt][nt][3]=0.f; }
  const unsigned short* __restrict__ Asrc = (g<2)? Xh : Xl;
  const int koff = (g&1)*8;
  for (int kc=0; kc<8; ++kc){
    s16x8 a[2];
#pragma unroll
    for (int mt=0;mt<2;++mt)
      a[mt] = *(const s16x8*)(Asrc + ((long)(mbase + mt*16 + lc))*128 + kc*16 + koff);
#pragma unroll
    for (int nt=0;nt<8;++nt){
      const int fi = (kc*2+(g&1))*128 + nt*16 + lc;
      s16x8 b1 = ((const s16x8*)wh)[fi];
      s16x8 b2 = ((const s16x8*)wl)[fi];
#pragma unroll
      for (int mt=0;mt<2;++mt){
        acc[mt][nt] = __builtin_amdgcn_mfma_f32_16x16x32_bf16(a[mt], b1, acc[mt][nt], 0,0,0);
        acc[mt][nt] = __builtin_amdgcn_mfma_f32_16x16x32_bf16(a[mt], b2, acc[mt][nt], 0,0,0);
      }
    }
  }
#pragma unroll
  for (int nt=0;nt<8;++nt){
    const float bb = bias[nt*16 + lc];
#pragma unroll
    for (int mt=0;mt<2;++mt){
#pragma unroll
      for (int r=0;r<4;++r){
        const int row = mbase + mt*16 + g*4 + r;
        float v = acc[mt][nt][r] + bb;
        const int b = row>>12, li = row&4095;
        const long o = (((long)(b*NH + nt))*L + li)*HD + lc;
        if (p==2){
          Vo[o] = v;
        } else {
          if (p==0) v *= QSCALE;
          const unsigned short h = f2bf(v);
          const unsigned short lo2 = f2bf(v - bf2f(h));
          if (p==0){ Qh[o]=h; Ql[o]=lo2; } else { Kh[o]=h; Kl[o]=lo2; }
        }
      }
    }
  }
}

// ---------------- K2: partial row-max (exp2 domain), LDS-staged B, single barrier ----------------
// grid (16 qt, 16 bh, 8 ks), block 256 = 4 waves. Per block: stage K-slice (32KB) once,
// then barrier-free MFMA loop reading B-fragments from LDS.
__global__ __launch_bounds__(256) void rowmax_k(
    const unsigned short* __restrict__ Qh, const unsigned short* __restrict__ Ql,
    const unsigned short* __restrict__ Kh, const unsigned short* __restrict__ Kl,
    float* __restrict__ mpart)
{
  const int bh = blockIdx.y, qt = blockIdx.x, ks = blockIdx.z;
  const int t = threadIdx.x, w = t>>6, l = t&63;
  const int half = (l>>4)&1, part = l>>5, lc = l&15;
  __shared__ __align__(16) unsigned short khs[SLICE*HD];   // 16KB
  __shared__ __align__(16) unsigned short kls[SLICE*HD];   // 16KB
  {
    const uint4* gh = (const uint4*)(Kh + ((long)bh*L + ks*SLICE)*HD);
    const uint4* gl = (const uint4*)(Kl + ((long)bh*L + ks*SLICE)*HD);
    uint4* sh = (uint4*)khs; uint4* sl = (uint4*)kls;
#pragma unroll
    for (int i=0;i<4;++i){ sh[t + i*256] = gh[t + i*256]; sl[t + i*256] = gl[t + i*256]; }
  }
  s16x8 aq[4];
  {
    const unsigned short* Qsrc = part ? Ql : Qh;
#pragma unroll
    for (int m=0;m<4;++m){
      const int row = qt*256 + w*64 + m*16 + lc;
      aq[m] = *(const s16x8*)(Qsrc + (((long)bh*L + row)*HD) + half*8);
    }
  }
  __syncthreads();
  f32x4 fz; fz[0]=0.f; fz[1]=0.f; fz[2]=0.f; fz[3]=0.f;
  f32x4 rmax[4];
#pragma unroll
  for (int m=0;m<4;++m){ rmax[m][0]=rmax[m][1]=rmax[m][2]=rmax[m][3]=-3.4e38f; }
  const int boff = lc*HD + half*8;
#pragma unroll 2
  for (int kk=0; kk<KK; ++kk){
    s16x8 b1 = *(const s16x8*)(khs + kk*256 + boff);
    s16x8 b2 = *(const s16x8*)(kls + kk*256 + boff);
#pragma unroll
    for (int m=0;m<4;++m){
      f32x4 acc = __builtin_amdgcn_mfma_f32_16x16x32_bf16(aq[m], b2, fz, 0,0,0);
      acc = __builtin_amdgcn_mfma_f32_16x16x32_bf16(aq[m], b1, acc, 0,0,0);
#pragma unroll
      for (int r=0;r<4;++r) rmax[m][r] = fmaxf(rmax[m][r], acc[r]);
    }
  }
#pragma unroll
  for (int m=0;m<4;++m){
#pragma unroll
    for (int r=0;r<4;++r){
      float v = rmax[m][r];
      v = fmaxf(v, __shfl_xor(v, 1));
      v = fmaxf(v, __shfl_xor(v, 2));
      v = fmaxf(v, __shfl_xor(v, 4));
      v = fmaxf(v, __shfl_xor(v, 8));
      rmax[m][r] = v;
    }
  }
  if (lc == 0){
    const int q4 = l>>4;
#pragma unroll
    for (int m=0;m<4;++m){
#pragma unroll
      for (int r=0;r<4;++r){
        const int row = qt*256 + w*64 + m*16 + q4*4 + r;
        mpart[((long)ks*NBH + bh)*L + row] = rmax[m][r];
      }
    }
  }
}

// ---------------- K2b: reduce partial maxes -> w_q = exp2(-m'_q) ----------------
__global__ __launch_bounds__(256) void mreduce(
    const float* __restrict__ mpart, float* __restrict__ wq)
{
  const int i = blockIdx.x*256 + threadIdx.x;  // 0 .. NBH*L-1
  float m = -3.4e38f;
#pragma unroll
  for (int p=0;p<NSPLIT;++p) m = fmaxf(m, mpart[(long)p*NBH*L + i]);
  wq[i] = fast_exp2(-m);
}

// ---------------- K3: partial column sums of exp2(s')*w_q, LDS-staged B, single barrier ----------------
// grid (16 kt, 16 bh, 8 qs), block 256 = 4 waves. Per block: stage Q-slice (32KB) + w (2KB) once,
// then barrier-free MFMA+exp loop reading from LDS.
__global__ __launch_bounds__(256) void colexp_k(
    const unsigned short* __restrict__ Kh, const unsigned short* __restrict__ Kl,
    const unsigned short* __restrict__ Qh, const unsigned short* __restrict__ Ql,
    const float* __restrict__ wq, float* __restrict__ cspart)
{
  const int bh = blockIdx.y, kt = blockIdx.x, qs = blockIdx.z;
  const int t = threadIdx.x, w = t>>6, l = t&63;
  const int half = (l>>4)&1, part = l>>5, lc = l&15;
  __shared__ __align__(16) unsigned short qhs[SLICE*HD];   // 16KB
  __shared__ __align__(16) unsigned short qls[SLICE*HD];   // 16KB
  __shared__ float ws_s[SLICE];                            // 2KB
  {
    const uint4* gh = (const uint4*)(Qh + ((long)bh*L + qs*SLICE)*HD);
    const uint4* gl = (const uint4*)(Ql + ((long)bh*L + qs*SLICE)*HD);
    uint4* sh = (uint4*)qhs; uint4* sl = (uint4*)qls;
#pragma unroll
    for (int i=0;i<4;++i){ sh[t + i*256] = gh[t + i*256]; sl[t + i*256] = gl[t + i*256]; }
    const float* wg = wq + (long)bh*L + qs*SLICE;
    ws_s[t] = wg[t];
    ws_s[t+256] = wg[t+256];
  }
  s16x8 ak[4];
  {
    const unsigned short* Ksrc = part ? Kl : Kh;
#pragma unroll
    for (int m=0;m<4;++m){
      const int key = kt*256 + w*64 + m*16 + lc;
      ak[m] = *(const s16x8*)(Ksrc + (((long)bh*L + key)*HD) + half*8);
    }
  }
  __syncthreads();
  f32x4 fz; fz[0]=0.f; fz[1]=0.f; fz[2]=0.f; fz[3]=0.f;
  f32x4 csum[4];
#pragma unroll
  for (int m=0;m<4;++m){ csum[m][0]=0.f; csum[m][1]=0.f; csum[m][2]=0.f; csum[m][3]=0.f; }
  const int boff = lc*HD + half*8;
#pragma unroll 2
  for (int kk=0; kk<KK; ++kk){
    s16x8 b1 = *(const s16x8*)(qhs + kk*256 + boff);
    s16x8 b2 = *(const s16x8*)(qls + kk*256 + boff);
    const float cw = ws_s[kk*16 + lc];
#pragma unroll
    for (int m=0;m<4;++m){
      f32x4 acc = __builtin_amdgcn_mfma_f32_16x16x32_bf16(ak[m], b2, fz, 0,0,0);
      acc = __builtin_amdgcn_mfma_f32_16x16x32_bf16(ak[m], b1, acc, 0,0,0);
#pragma unroll
      for (int r=0;r<4;++r)
        csum[m][r] = fmaf(fast_exp2(acc[r]), cw, csum[m][r]);
    }
  }
#pragma unroll
  for (int m=0;m<4;++m){
#pragma unroll
    for (int r=0;r<4;++r){
      float v = csum[m][r];
      v += __shfl_xor(v, 1);
      v += __shfl_xor(v, 2);
      v += __shfl_xor(v, 4);
      v += __shfl_xor(v, 8);
      csum[m][r] = v;
    }
  }
  if (lc == 0){
    const int k4 = l>>4;
#pragma unroll
    for (int m=0;m<4;++m){
#pragma unroll
      for (int r=0;r<4;++r){
        const int key = kt*256 + w*64 + m*16 + k4*4 + r;
        cspart[((long)qs*NBH + bh)*L + key] = csum[m][r];
      }
    }
  }
}

// ---------------- K4: exact 3-level radix-select top-41 + gather Ks/Vs (csreduce fused) ----------------
__global__ __launch_bounds__(256) void topk_gather(
    const float* __restrict__ cspart,
    const unsigned short* __restrict__ Kh, const unsigned short* __restrict__ Kl,
    const float* __restrict__ V,
    float* __restrict__ Ks, float* __restrict__ Vs)
{
  const int bh = blockIdx.x;
  const int t = threadIdx.x;
  __shared__ float vals[4096];
  __shared__ unsigned hist[2048];
  __shared__ unsigned suf[256];
  __shared__ int meta[4];           // 0:B 1:nab 2:ngt 3:ntie
  __shared__ int sel[SK];
  __shared__ int sorted[SK];
  __shared__ int tiei[4096];

  for (int i=t; i<1024; i+=256){
    float4 s = {0.f,0.f,0.f,0.f};
#pragma unroll
    for (int p=0;p<NSPLIT;++p){
      float4 v = *(const float4*)(cspart + ((long)p*NBH + bh)*L + i*4);
      s.x += v.x; s.y += v.y; s.z += v.z; s.w += v.w;
    }
    *(float4*)&vals[i*4] = s;
  }
  __syncthreads();

  int target = SK;
  unsigned B1 = 0, P2 = 0, T = 0;
#pragma unroll
  for (int pass=0; pass<3; ++pass){
    const int nb = (pass<2) ? 2048 : 1024;
    const int chunk = nb >> 8;
    for (int i=t;i<nb;i+=256) hist[i]=0u;
    __syncthreads();
    for (int i=t;i<4096;i+=256){
      const unsigned u = __float_as_uint(vals[i]);
      bool ok; int bk;
      if (pass==0){ ok = true;              bk = (int)(u>>21); }
      else if (pass==1){ ok = ((u>>21)==B1); bk = (int)((u>>10)&0x7FFu); }
      else { ok = ((u>>10)==P2);            bk = (int)(u&0x3FFu); }
      if (ok) atomicAdd(&hist[bk], 1u);
    }
    __syncthreads();
    {
      unsigned c=0;
#pragma unroll
      for (int b=0;b<8;++b) if (b<chunk) c += hist[t*chunk+b];
      suf[t]=c;
    }
    __syncthreads();
    for (int off=1; off<256; off<<=1){
      unsigned add = (t+off<256)? suf[t+off] : 0u;
      __syncthreads();
      suf[t] += add;
      __syncthreads();
    }
    {
      const unsigned mysuf = suf[t];
      const unsigned nxt = (t==255)?0u:suf[t+1];
      if (mysuf >= (unsigned)target && nxt < (unsigned)target){
        unsigned running = nxt;
        for (int b=t*chunk+chunk-1; b>=t*chunk; --b){
          const unsigned h = hist[b];
          if (running + h >= (unsigned)target){ meta[0]=b; meta[1]=(int)running; break; }
          running += h;
        }
      }
    }
    __syncthreads();
    const unsigned B = (unsigned)meta[0];
    target -= meta[1];
    if (pass==0) B1 = B;
    else if (pass==1) P2 = (B1<<11)|B;
    else T = (P2<<10)|B;
    __syncthreads();
  }
  if (t==0){ meta[2]=0; meta[3]=0; }
  __syncthreads();
  for (int i=t;i<4096;i+=256){
    const unsigned u = __float_as_uint(vals[i]);
    if (u > T){ int p = atomicAdd(&meta[2],1); sel[p]=i; }
    else if (u == T){ int p = atomicAdd(&meta[3],1); tiei[p]=i; }
  }
  __syncthreads();
  const int ngt = meta[2];
  const int ntie = meta[3];
  for (int j=t; j<ntie; j+=256){
    const int x = tiei[j];
    int rk=0;
    for (int k=0;k<ntie;++k) rk += (tiei[k] < x);
    if (rk < target) sel[ngt+rk] = x;
  }
  __syncthreads();
  if (t<SK){
    int x=sel[t]; int rk=0;
    for (int j=0;j<SK;++j) rk += (sel[j]<x);
    sorted[rk]=x;
  }
  __syncthreads();
  for (int i=t;i<SK*HD;i+=256){
    const int j=i>>4, dd=i&15;
    const int key=sorted[j];
    const long src=((long)bh*L+key)*HD+dd;
    Ks[(long)bh*SK*HD+i]=bf2f(Kh[src])+bf2f(Kl[src]);
    Vs[(long)bh*SK*HD+i]=V[src];
  }
}

// ---------------- K5: sampled attention — lane-pair split over keys ----------------
__global__ __launch_bounds__(256) void sattn(
    const unsigned short* __restrict__ Qh, const unsigned short* __restrict__ Ql,
    const float* __restrict__ Ks, const float* __restrict__ Vs,
    unsigned short* __restrict__ AOh, unsigned short* __restrict__ AOl)
{
  const int bh = blockIdx.y, qb = blockIdx.x;
  const int t = threadIdx.x;
  __shared__ float ks[SK*HD], vs[SK*HD];
  for (int i=t; i<SK*HD; i+=256){
    ks[i] = Ks[(long)bh*SK*HD + i];
    vs[i] = Vs[(long)bh*SK*HD + i];
  }
  __syncthreads();
  const int q = qb*128 + (t>>1);
  const int half = t&1;
  const long qo = ((long)bh*L + q)*HD;
  float qv[16];
  {
    s16x8 h0 = *(const s16x8*)(Qh+qo);
    s16x8 h1 = *(const s16x8*)(Qh+qo+8);
    s16x8 l0 = *(const s16x8*)(Ql+qo);
    s16x8 l1 = *(const s16x8*)(Ql+qo+8);
#pragma unroll
    for (int d=0; d<8; ++d){
      qv[d]   = bf2f((unsigned short)h0[d]) + bf2f((unsigned short)l0[d]);
      qv[d+8] = bf2f((unsigned short)h1[d]) + bf2f((unsigned short)l1[d]);
    }
  }
  float mrun = -3.4e38f, lrun = 0.f, out[16];
#pragma unroll
  for (int d=0; d<16; ++d) out[d] = 0.f;
  for (int j=half; j<SK; j+=2){
    float4 k0 = *(const float4*)&ks[j*HD+0];
    float4 k1 = *(const float4*)&ks[j*HD+4];
    float4 k2 = *(const float4*)&ks[j*HD+8];
    float4 k3 = *(const float4*)&ks[j*HD+12];
    float s = qv[0]*k0.x;
    s = fmaf(qv[1],k0.y,s); s = fmaf(qv[2],k0.z,s); s = fmaf(qv[3],k0.w,s);
    s = fmaf(qv[4],k1.x,s); s = fmaf(qv[5],k1.y,s); s = fmaf(qv[6],k1.z,s); s = fmaf(qv[7],k1.w,s);
    s = fmaf(qv[8],k2.x,s); s = fmaf(qv[9],k2.y,s); s = fmaf(qv[10],k2.z,s); s = fmaf(qv[11],k2.w,s);
    s = fmaf(qv[12],k3.x,s); s = fmaf(qv[13],k3.y,s); s = fmaf(qv[14],k3.z,s); s = fmaf(qv[15],k3.w,s);
    if (s > mrun){
      const float c = fast_exp2(mrun - s);
      lrun *= c;
#pragma unroll
      for (int d=0; d<16; ++d) out[d] *= c;
      mrun = s;
    }
    const float p = fast_exp2(s - mrun);
    lrun += p;
    float4 v0 = *(const float4*)&vs[j*HD+0];
    float4 v1 = *(const float4*)&vs[j*HD+4];
    float4 v2 = *(const float4*)&vs[j*HD+8];
    float4 v3 = *(const float4*)&vs[j*HD+12];
    out[0]=fmaf(p,v0.x,out[0]); out[1]=fmaf(p,v0.y,out[1]); out[2]=fmaf(p,v0.z,out[2]); out[3]=fmaf(p,v0.w,out[3]);
    out[4]=fmaf(p,v1.x,out[4]); out[5]=fmaf(p,v1.y,out[5]); out[6]=fmaf(p,v1.z,out[6]); out[7]=fmaf(p,v1.w,out[7]);
    out[8]=fmaf(p,v2.x,out[8]); out[9]=fmaf(p,v2.y,out[9]); out[10]=fmaf(p,v2.z,out[10]); out[11]=fmaf(p,v2.w,out[11]);
    out[12]=fmaf(p,v3.x,out[12]); out[13]=fmaf(p,v3.y,out[13]); out[14]=fmaf(p,v3.z,out[14]); out[15]=fmaf(p,v3.w,out[15]);
  }
  // merge lane-pair online-softmax states
  const float mo = __shfl_xor(mrun, 1);
  const float lo = __shfl_xor(lrun, 1);
  const float mm = fmaxf(mrun, mo);
  const float cs_ = fast_exp2(mrun - mm);
  const float co_ = fast_exp2(mo - mm);
  const float ltot = fmaf(lrun, cs_, lo*co_);
  const float inv = 1.f / ltot;
#pragma unroll
  for (int d=0; d<16; ++d){
    const float ov = __shfl_xor(out[d], 1);
    out[d] = fmaf(out[d]*cs_, inv, ov*co_*inv);
  }
  if (half == 0){
    const int b = bh>>3, h = bh&7;
    const long row = (long)b*L + q;
    unsigned short hv[16], lv[16];
#pragma unroll
    for (int d=0; d<16; ++d){
      const float v = out[d];
      hv[d] = f2bf(v);
      lv[d] = f2bf(v - bf2f(hv[d]));
    }
    unsigned short* oh = AOh + row*DM + h*HD;
    unsigned short* ol = AOl + row*DM + h*HD;
    *(uint4*)(oh)   = *(uint4*)(hv);
    *(uint4*)(oh+8) = *(uint4*)(hv+8);
    *(uint4*)(ol)   = *(uint4*)(lv);
    *(uint4*)(ol+8) = *(uint4*)(lv+8);
  }
}

// ---------------- K6: MFMA output projection ----------------
__global__ __launch_bounds__(256) void outproj_mfma(
    const unsigned short* __restrict__ AOh, const unsigned short* __restrict__ AOl,
    const unsigned short* __restrict__ Wph, const unsigned short* __restrict__ Wpl,
    const float* __restrict__ bo, float* __restrict__ out)
{
  __shared__ __align__(16) unsigned short wh[16384];
  __shared__ __align__(16) unsigned short wl[16384];
  const int t = threadIdx.x;
  {
    const uint4* gh = (const uint4*)(Wph + (long)3*16384);
    const uint4* gl = (const uint4*)(Wpl + (long)3*16384);
    uint4* sh = (uint4*)wh; uint4* sl = (uint4*)wl;
#pragma unroll
    for (int i=0;i<8;++i){ sh[t + i*256] = gh[t + i*256]; sl[t + i*256] = gl[t + i*256]; }
  }
  __syncthreads();
  const int w = t>>6, l = t&63;
  const int lc = l&15, g = l>>4;
  const int mbase = blockIdx.x*128 + w*32;
  f32x4 acc[2][8];
#pragma unroll
  for (int mt=0;mt<2;++mt)
#pragma unroll
    for (int nt=0;nt<8;++nt){ acc[mt][nt][0]=0.f; acc[mt][nt][1]=0.f; acc[mt][nt][2]=0.f; acc[mt][nt][3]=0.f; }
  const unsigned short* __restrict__ Asrc = (g<2)? AOh : AOl;
  const int koff = (g&1)*8;
  for (int kc=0; kc<8; ++kc){
    s16x8 a[2];
#pragma unroll
    for (int mt=0;mt<2;++mt)
      a[mt] = *(const s16x8*)(Asrc + ((long)(mbase + mt*16 + lc))*128 + kc*16 + koff);
#pragma unroll
    for (int nt=0;nt<8;++nt){
      const int fi = (kc*2+(g&1))*128 + nt*16 + lc;
      s16x8 b1 = ((const s16x8*)wh)[fi];
      s16x8 b2 = ((const s16x8*)wl)[fi];
#pragma unroll
      for (int mt=0;mt<2;++mt){
        acc[mt][nt] = __builtin_amdgcn_mfma_f32_16x16x32_bf16(a[mt], b1, acc[mt][nt], 0,0,0);
        acc[mt][nt] = __builtin_amdgcn_mfma_f32_16x16x32_bf16(a[mt], b2, acc[mt][nt], 0,0,0);
      }
    }
  }
#pragma unroll
  for (int nt=0;nt<8;++nt){
    const float bb = bo[nt*16 + lc];
#pragma unroll
    for (int mt=0;mt<2;++mt){
#pragma unroll
      for (int r=0;r<4;++r){
        const int row = mbase + mt*16 + g*4 + r;
        out[(long)row*DM + nt*16 + lc] = acc[mt][nt][r] + bb;
      }
    }
  }
}

extern "C" void kernel_launch(void* const* d_in, const int* in_sizes, int n_in,
                              void* d_out, int out_size, void* d_ws, size_t ws_size,
                              hipStream_t stream)
{
  const float* x  = (const float*)d_in[0];
  const float* Wq = (const float*)d_in[1];
  const float* bq = (const float*)d_in[2];
  const float* Wk = (const float*)d_in[3];
  const float* bk = (const float*)d_in[4];
  const float* Wv = (const float*)d_in[5];
  const float* bv = (const float*)d_in[6];
  const float* Wo = (const float*)d_in[7];
  const float* bo = (const float*)d_in[8];
  float* out = (float*)d_out;

  char* wsp = (char*)d_ws;
  size_t o = 0;
  auto alloc = [&](size_t bytes)->char*{
    char* p = wsp + o; o += (bytes + 255) & ~(size_t)255; return p;
  };
  unsigned short* Qh = (unsigned short*)alloc((size_t)NBH*L*HD*2);
  unsigned short* Ql = (unsigned short*)alloc((size_t)NBH*L*HD*2);
  unsigned short* Kh = (unsigned short*)alloc((size_t)NBH*L*HD*2);
  unsigned short* Kl = (unsigned short*)alloc((size_t)NBH*L*HD*2);
  float* Vv    = (float*)alloc((size_t)NBH*L*HD*4);
  float* mpart = (float*)alloc((size_t)NSPLIT*NBH*L*4);
  float* cspart= (float*)alloc((size_t)NSPLIT*NBH*L*4);
  float* wqv   = (float*)alloc((size_t)NBH*L*4);
  float* Ks    = (float*)alloc((size_t)NBH*SK*HD*4);
  float* Vs    = (float*)alloc((size_t)NBH*SK*HD*4);
  unsigned short* Xh  = (unsigned short*)alloc((size_t)2*L*DM*2);
  unsigned short* Xl  = (unsigned short*)alloc((size_t)2*L*DM*2);
  unsigned short* AOh = (unsigned short*)alloc((size_t)2*L*DM*2);
  unsigned short* AOl = (unsigned short*)alloc((size_t)2*L*DM*2);
  unsigned short* Wph = (unsigned short*)alloc((size_t)4*16384*2);
  unsigned short* Wpl = (unsigned short*)alloc((size_t)4*16384*2);

  prep<<<1280,256,0,stream>>>(x,Wq,Wk,Wv,Wo,Xh,Xl,Wph,Wpl);
  proj_mfma<<<dim3(64,3),256,0,stream>>>(Xh,Xl,Wph,Wpl,bq,bk,bv,Qh,Ql,Kh,Kl,Vv);
  rowmax_k<<<dim3(16,16,NSPLIT),256,0,stream>>>(Qh,Ql,Kh,Kl,mpart);
  mreduce<<<NBH*L/256,256,0,stream>>>(mpart,wqv);
  colexp_k<<<dim3(16,16,NSPLIT),256,0,stream>>>(Kh,Kl,Qh,Ql,wqv,cspart);
  topk_gather<<<16,256,0,stream>>>(cspart,Kh,Kl,Vv,Ks,Vs);
  sattn<<<dim3(32,16),256,0,stream>>>(Qh,Ql,Ks,Vs,AOh,AOl);
  outproj_mfma<<<64,256,0,stream>>>(AOh,AOl,Wph,Wpl,bo,out);
}